// Round 1
// baseline (204.165 us; speedup 1.0000x reference)
//
#include <hip/hip_runtime.h>

typedef __attribute__((ext_vector_type(8))) short s16x8;
typedef __attribute__((ext_vector_type(4))) float f32x4;
typedef unsigned short u16;
typedef unsigned int u32;

#define LOG2E 1.4426950408889634f

__device__ __forceinline__ u16 f2bf(float x) {
  u32 u = __float_as_uint(x);
  u += 0x7FFFu + ((u >> 16) & 1u);
  return (u16)(u >> 16);
}

__device__ __forceinline__ void gl_lds16(const void* g, void* l) {
  __builtin_amdgcn_global_load_lds((const __attribute__((address_space(1))) void*)g,
                                   (__attribute__((address_space(3))) void*)l, 16, 0, 0);
}

#define MFMA16(a, b, c) __builtin_amdgcn_mfma_f32_16x16x32_bf16((a), (b), (c), 0, 0, 0)

// ---------------- prep kernels ----------------

__global__ __launch_bounds__(256) void cast_hs(const float* __restrict__ src,
                                               u16* __restrict__ dst) {
  const int i = blockIdx.x * 256 + threadIdx.x;  // 524288 total
  const float4* s4 = (const float4*)src;
  float4 a = s4[i * 2];
  float4 b = s4[i * 2 + 1];
  s16x8 o;
  o[0] = (short)f2bf(a.x); o[1] = (short)f2bf(a.y);
  o[2] = (short)f2bf(a.z); o[3] = (short)f2bf(a.w);
  o[4] = (short)f2bf(b.x); o[5] = (short)f2bf(b.y);
  o[6] = (short)f2bf(b.z); o[7] = (short)f2bf(b.w);
  *(s16x8*)&dst[i * 8] = o;
}

// Wt[n][k] = bf16(W[k][n]) for a 1024x1024 weight
__global__ __launch_bounds__(256) void wtrans(const float* __restrict__ W,
                                              u16* __restrict__ Wt) {
  const int t = threadIdx.x;
  const int n = blockIdx.x * 64 + (t & 63);
  const int kb = blockIdx.y * 32 + (t >> 6) * 8;
  s16x8 o;
#pragma unroll
  for (int j = 0; j < 8; ++j) o[j] = (short)f2bf(W[(kb + j) * 1024 + n]);
  *(s16x8*)&Wt[n * 1024 + kb] = o;
}

// biasT[h*4096 + (delta+2047)] = table[bucket(delta)][h] * log2e
__global__ __launch_bounds__(256) void bias_table(const float* __restrict__ tbl,
                                                  float* __restrict__ biasT) {
  const int i = blockIdx.x * 256 + threadIdx.x;  // 65536
  const int h = i >> 12, dp = i & 4095;
  const int delta = dp - 2047;
  const int rp = delta < 0 ? -delta : delta;
  int bucket = delta > 0 ? 16 : 0;
  if (rp < 8)
    bucket += rp;
  else
    bucket += 8 + (rp >= 12) + (rp >= 16) + (rp >= 23) + (rp >= 32) +
              (rp >= 46) + (rp >= 64) + (rp >= 91);
  biasT[i] = tbl[bucket * 16 + h] * LOG2E;
}

// VT[(bh*64+d)*2048 + s] = V[(b*2048+s)*1024 + h*64 + d]
__global__ __launch_bounds__(256) void vtrans(const u16* __restrict__ V,
                                              u16* __restrict__ VT) {
  const int tid = threadIdx.x;
  const int bh = blockIdx.y;
  const int b = bh >> 4, h = bh & 15;
  const int s0 = blockIdx.x * 32;
  const int d = tid & 63;
  const int si = tid >> 6;
  s16x8 o;
#pragma unroll
  for (int j = 0; j < 8; ++j)
    o[j] = (short)V[(b * 2048 + s0 + si * 8 + j) * 1024 + h * 64 + d];
  *(s16x8*)&VT[(bh * 64 + d) * 2048 + s0 + si * 8] = o;
}

// ---------------- GEMM core: C[128x128] tile, A[M,1024] @ Bt[N,1024]^T ----------------
// LDS tiles [128 rows][64 k] bf16, XOR-swizzled (byte ^= (row&7)<<4) via
// pre-swizzled global source (global_load_lds writes linearly).

__device__ __forceinline__ void gemm_core(const u16* __restrict__ A,
                                          const u16* __restrict__ Bt,
                                          int m0, int n0,
                                          u16* As, u16* Bs, f32x4 acc[4][4]) {
  const int tid = threadIdx.x;
  const int w = tid >> 6, l = tid & 63, g = l >> 4, m15 = l & 15;
  const int wr = (w >> 1) * 64, wc = (w & 1) * 64;
#pragma unroll
  for (int i = 0; i < 4; ++i)
#pragma unroll
    for (int j = 0; j < 4; ++j) acc[i][j] = (f32x4){0.f, 0.f, 0.f, 0.f};

  for (int kt = 0; kt < 16; ++kt) {
    const int k0 = kt * 64;
    __syncthreads();
#pragma unroll
    for (int c = 0; c < 4; ++c) {
      const int idx = c * 256 + tid;
      const int row = idx >> 3, col16 = idx & 7;
      const int scol = col16 ^ (row & 7);
      gl_lds16(&A[(m0 + row) * 1024 + k0 + scol * 8], (char*)As + c * 4096 + w * 1024);
      gl_lds16(&Bt[(n0 + row) * 1024 + k0 + scol * 8], (char*)Bs + c * 4096 + w * 1024);
    }
    __syncthreads();
#pragma unroll
    for (int ks = 0; ks < 2; ++ks) {
      s16x8 af[4], bf[4];
#pragma unroll
      for (int mf = 0; mf < 4; ++mf) {
        const int row = wr + mf * 16 + m15;
        af[mf] = *(const s16x8*)&As[(row * 8 + ((ks * 4 + g) ^ (row & 7))) * 8];
      }
#pragma unroll
      for (int nf = 0; nf < 4; ++nf) {
        const int row = wc + nf * 16 + m15;
        bf[nf] = *(const s16x8*)&Bs[(row * 8 + ((ks * 4 + g) ^ (row & 7))) * 8];
      }
#pragma unroll
      for (int mf = 0; mf < 4; ++mf)
#pragma unroll
        for (int nf = 0; nf < 4; ++nf)
          acc[mf][nf] = MFMA16(af[mf], bf[nf], acc[mf][nf]);
    }
  }
}

// QKV: X[4096,1024] @ Wt[3072,1024]^T -> Q(scaled)/K/V bf16 [4096,1024]
__global__ __launch_bounds__(256) void gemm_qkv(const u16* __restrict__ X,
                                                const u16* __restrict__ Wt,
                                                u16* __restrict__ Q,
                                                u16* __restrict__ Kb,
                                                u16* __restrict__ Vb) {
  __shared__ u16 As[8192], Bs[8192];
  f32x4 acc[4][4];
  const int m0 = blockIdx.x * 128, n0 = blockIdx.y * 128;
  gemm_core(X, Wt, m0, n0, As, Bs, acc);

  const int tid = threadIdx.x;
  const int w = tid >> 6, l = tid & 63, g = l >> 4, m15 = l & 15;
  const int wr = (w >> 1) * 64, wc = (w & 1) * 64;
  const int nsel = n0 >> 10;
  u16* dst = nsel == 0 ? Q : (nsel == 1 ? Kb : Vb);
  const float scale = nsel == 0 ? 0.125f * LOG2E : 1.0f;
  const int ncol0 = (n0 & 1023) + wc;
#pragma unroll
  for (int mf = 0; mf < 4; ++mf) {
    const int rbase = m0 + wr + mf * 16 + g * 4;
#pragma unroll
    for (int nf = 0; nf < 4; ++nf) {
      const int col = ncol0 + nf * 16 + m15;
#pragma unroll
      for (int r = 0; r < 4; ++r)
        dst[(rbase + r) * 1024 + col] = f2bf(acc[mf][nf][r] * scale);
    }
  }
}

// out-proj: CTX[4096,1024] @ Wot[1024,1024]^T -> fp32 out
__global__ __launch_bounds__(256) void gemm_out(const u16* __restrict__ CTX,
                                                const u16* __restrict__ Wot,
                                                float* __restrict__ Out) {
  __shared__ u16 As[8192], Bs[8192];
  f32x4 acc[4][4];
  const int m0 = blockIdx.x * 128, n0 = blockIdx.y * 128;
  gemm_core(CTX, Wot, m0, n0, As, Bs, acc);

  const int tid = threadIdx.x;
  const int w = tid >> 6, l = tid & 63, g = l >> 4, m15 = l & 15;
  const int wr = (w >> 1) * 64, wc = (w & 1) * 64;
#pragma unroll
  for (int mf = 0; mf < 4; ++mf) {
    const int rbase = m0 + wr + mf * 16 + g * 4;
#pragma unroll
    for (int nf = 0; nf < 4; ++nf) {
      const int col = n0 + wc + nf * 16 + m15;
#pragma unroll
      for (int r = 0; r < 4; ++r)
        Out[(rbase + r) * 1024 + col] = acc[mf][nf][r];
    }
  }
}

// ---------------- flash attention ----------------
// 1 block = (b, h, 64 q-rows); 4 waves x 16 q-rows. KV tiles of 64.
// Q pre-scaled by 0.125*log2e; bias pre-scaled by log2e; softmax in exp2 domain.

__global__ __launch_bounds__(256) void attn_kernel(const u16* __restrict__ Qg,
                                                   const u16* __restrict__ Kg,
                                                   const u16* __restrict__ VTg,
                                                   const float* __restrict__ biasT,
                                                   u16* __restrict__ CTX) {
  __shared__ float biasL[2112];
  __shared__ u16 KT[4096];    // [64 kv][64 kdim] swizzled
  __shared__ u16 VTs[4096];   // [64 dv][64 kv]  swizzled
  __shared__ u16 P[4][1024];  // per-wave [16 q][64 kv] swizzled

  const int tid = threadIdx.x;
  const int w = tid >> 6, l = tid & 63, g = l >> 4, m15 = l & 15;
  const int bh = blockIdx.y, b = bh >> 4, h = bh & 15;
  const int q0 = blockIdx.x * 64;

  {
    const int base = h * 4096 + 1984 - q0;
    for (int i = tid; i < 2112; i += 256) biasL[i] = biasT[base + i];
  }

  const int qrow = q0 + w * 16 + m15;
  const u16* qp = &Qg[(b * 2048 + qrow) * 1024 + h * 64 + g * 8];
  const s16x8 aq0 = *(const s16x8*)qp;
  const s16x8 aq1 = *(const s16x8*)(qp + 32);

  f32x4 o[4];
  float m_[4], ls[4];
#pragma unroll
  for (int d = 0; d < 4; ++d) o[d] = (f32x4){0.f, 0.f, 0.f, 0.f};
#pragma unroll
  for (int r = 0; r < 4; ++r) { m_[r] = -1e30f; ls[r] = 0.f; }

  const int R0 = w * 16 + g * 4;
  u16* Pw = &P[w][0];

  for (int kv0 = 0; kv0 < 2048; kv0 += 64) {
    __syncthreads();
#pragma unroll
    for (int c = 0; c < 2; ++c) {
      const int idx = c * 256 + tid;
      const int row = idx >> 3, col16 = idx & 7;
      const int scol = col16 ^ (row & 7);
      gl_lds16(&Kg[(b * 2048 + kv0 + row) * 1024 + h * 64 + scol * 8],
               (char*)KT + c * 4096 + w * 1024);
      gl_lds16(&VTg[(bh * 64 + row) * 2048 + kv0 + scol * 8],
               (char*)VTs + c * 4096 + w * 1024);
    }
    __syncthreads();

    // S = Q K^T  (16 q-rows x 64 kv-cols per wave)
    f32x4 s[4];
#pragma unroll
    for (int c = 0; c < 4; ++c) s[c] = (f32x4){0.f, 0.f, 0.f, 0.f};
#pragma unroll
    for (int ks = 0; ks < 2; ++ks) {
      const s16x8 a = ks ? aq1 : aq0;
#pragma unroll
      for (int c = 0; c < 4; ++c) {
        const int row = c * 16 + m15;
        const s16x8 bk = *(const s16x8*)&KT[(row * 8 + ((ks * 4 + g) ^ (row & 7))) * 8];
        s[c] = MFMA16(a, bk, s[c]);
      }
    }

    // bias + online softmax (rows R0+r, per-row reduce over 16-lane group)
    float tmax[4], tsum[4], corr[4];
#pragma unroll
    for (int r = 0; r < 4; ++r) {
      const int bidx = kv0 + m15 - (R0 + r) + 63;
      float s0 = s[0][r] + biasL[bidx];
      float s1 = s[1][r] + biasL[bidx + 16];
      float s2 = s[2][r] + biasL[bidx + 32];
      float s3 = s[3][r] + biasL[bidx + 48];
      s[0][r] = s0; s[1][r] = s1; s[2][r] = s2; s[3][r] = s3;
      tmax[r] = fmaxf(fmaxf(s0, s1), fmaxf(s2, s3));
    }
#pragma unroll
    for (int dx = 1; dx < 16; dx <<= 1) {
#pragma unroll
      for (int r = 0; r < 4; ++r) tmax[r] = fmaxf(tmax[r], __shfl_xor(tmax[r], dx));
    }
#pragma unroll
    for (int r = 0; r < 4; ++r) {
      const float mn = fmaxf(m_[r], tmax[r]);
      corr[r] = exp2f(m_[r] - mn);
      m_[r] = mn;
    }
#pragma unroll
    for (int c = 0; c < 4; ++c) {
#pragma unroll
      for (int r = 0; r < 4; ++r) s[c][r] = exp2f(s[c][r] - m_[r]);
    }
#pragma unroll
    for (int r = 0; r < 4; ++r) tsum[r] = s[0][r] + s[1][r] + s[2][r] + s[3][r];
#pragma unroll
    for (int dx = 1; dx < 16; dx <<= 1) {
#pragma unroll
      for (int r = 0; r < 4; ++r) tsum[r] += __shfl_xor(tsum[r], dx);
    }
#pragma unroll
    for (int r = 0; r < 4; ++r) ls[r] = ls[r] * corr[r] + tsum[r];
#pragma unroll
    for (int d = 0; d < 4; ++d) {
#pragma unroll
      for (int r = 0; r < 4; ++r) o[d][r] *= corr[r];
    }

    // P -> LDS (bf16, swizzled) to convert D-layout to A-layout
#pragma unroll
    for (int c = 0; c < 4; ++c) {
#pragma unroll
      for (int r = 0; r < 4; ++r) {
        const int Rr = g * 4 + r;
        const int byt = Rr * 128 + (((c * 16 + m15) * 2) ^ ((Rr & 7) << 4));
        Pw[byt >> 1] = f2bf(s[c][r]);
      }
    }

    // O += P @ V
#pragma unroll
    for (int ks = 0; ks < 2; ++ks) {
      const s16x8 pa =
          *(const s16x8*)&Pw[(m15 * 128 + ((ks * 64 + g * 16) ^ ((m15 & 7) << 4))) >> 1];
#pragma unroll
      for (int d = 0; d < 4; ++d) {
        const int rowv = d * 16 + m15;
        const s16x8 bv = *(const s16x8*)&VTs[(rowv * 8 + ((ks * 4 + g) ^ (rowv & 7))) * 8];
        o[d] = MFMA16(pa, bv, o[d]);
      }
    }
  }

  float inv[4];
#pragma unroll
  for (int r = 0; r < 4; ++r) inv[r] = 1.0f / ls[r];
  const int orow = b * 2048 + q0 + w * 16 + g * 4;
  const int ocol = h * 64 + m15;
#pragma unroll
  for (int d = 0; d < 4; ++d) {
#pragma unroll
    for (int r = 0; r < 4; ++r)
      CTX[(orow + r) * 1024 + ocol + d * 16] = f2bf(o[d][r] * inv[r]);
  }
}

// ---------------- launch ----------------

extern "C" void kernel_launch(void* const* d_in, const int* in_sizes, int n_in,
                              void* d_out, int out_size, void* d_ws, size_t ws_size,
                              hipStream_t stream) {
  (void)in_sizes; (void)n_in; (void)out_size; (void)ws_size;
  const float* hs  = (const float*)d_in[0];
  const float* Wq  = (const float*)d_in[1];
  const float* Wk  = (const float*)d_in[2];
  const float* Wv  = (const float*)d_in[3];
  const float* Wo  = (const float*)d_in[4];
  const float* tbl = (const float*)d_in[5];

  char* ws = (char*)d_ws;
  u16* hsb   = (u16*)(ws);                 // 8,388,608 B  bf16 hidden
  u16* wt    = (u16*)(ws + 8388608);       // 6,291,456 B  Wq^T|Wk^T|Wv^T bf16 [3072][1024]
  u16* wot   = (u16*)(ws + 14680064);      // 2,097,152 B  Wo^T bf16
  u16* q     = (u16*)(ws + 16777216);      // 8,388,608 B  Q bf16 (scaled)
  u16* k     = (u16*)(ws + 25165824);      // 8,388,608 B  K bf16
  u16* v     = (u16*)(ws + 33554432);      // 8,388,608 B  V bf16
  u16* vt    = (u16*)(ws + 41943040);      // 8,388,608 B  V^T bf16 [32][64][2048]
  u16* ctx   = (u16*)(ws + 50331648);      // 8,388,608 B  attn output bf16
  float* biasT = (float*)(ws + 58720256);  //   262,144 B  bias table [16][4096]

  cast_hs<<<2048, 256, 0, stream>>>(hs, hsb);
  wtrans<<<dim3(16, 32), 256, 0, stream>>>(Wq, wt);
  wtrans<<<dim3(16, 32), 256, 0, stream>>>(Wk, wt + 1048576);
  wtrans<<<dim3(16, 32), 256, 0, stream>>>(Wv, wt + 2097152);
  wtrans<<<dim3(16, 32), 256, 0, stream>>>(Wo, wot);
  bias_table<<<256, 256, 0, stream>>>(tbl, biasT);
  gemm_qkv<<<dim3(32, 24), 256, 0, stream>>>(hsb, wt, q, k, v);
  vtrans<<<dim3(64, 32), 256, 0, stream>>>(v, vt);
  attn_kernel<<<dim3(32, 32), 256, 0, stream>>>(q, k, vt, biasT, ctx);
  gemm_out<<<dim3(32, 8), 256, 0, stream>>>(ctx, wot, (float*)d_out);
}

// Round 2
// 144.951 us; speedup vs baseline: 1.4085x; 1.4085x over previous
//
#include <hip/hip_runtime.h>

typedef __attribute__((ext_vector_type(8))) short s16x8;
typedef __attribute__((ext_vector_type(4))) float f32x4;
typedef unsigned short u16;
typedef unsigned int u32;

#define LOG2E 1.4426950408889634f

__device__ __forceinline__ u16 f2bf(float x) {
  u32 u = __float_as_uint(x);
  u += 0x7FFFu + ((u >> 16) & 1u);
  return (u16)(u >> 16);
}

__device__ __forceinline__ void gl_lds16(const void* g, void* l) {
  __builtin_amdgcn_global_load_lds((const __attribute__((address_space(1))) void*)g,
                                   (__attribute__((address_space(3))) void*)l, 16, 0, 0);
}

#define MFMA16(a, b, c) __builtin_amdgcn_mfma_f32_16x16x32_bf16((a), (b), (c), 0, 0, 0)

// ---------------- prep kernels ----------------

__global__ __launch_bounds__(256) void cast_hs(const float* __restrict__ src,
                                               u16* __restrict__ dst) {
  const int i = blockIdx.x * 256 + threadIdx.x;  // 524288 total
  const float4* s4 = (const float4*)src;
  float4 a = s4[i * 2];
  float4 b = s4[i * 2 + 1];
  s16x8 o;
  o[0] = (short)f2bf(a.x); o[1] = (short)f2bf(a.y);
  o[2] = (short)f2bf(a.z); o[3] = (short)f2bf(a.w);
  o[4] = (short)f2bf(b.x); o[5] = (short)f2bf(b.y);
  o[6] = (short)f2bf(b.z); o[7] = (short)f2bf(b.w);
  *(s16x8*)&dst[i * 8] = o;
}

// Wt[n][k] = bf16(W[k][n]) for a 1024x1024 weight
__global__ __launch_bounds__(256) void wtrans(const float* __restrict__ W,
                                              u16* __restrict__ Wt) {
  const int t = threadIdx.x;
  const int n = blockIdx.x * 64 + (t & 63);
  const int kb = blockIdx.y * 32 + (t >> 6) * 8;
  s16x8 o;
#pragma unroll
  for (int j = 0; j < 8; ++j) o[j] = (short)f2bf(W[(kb + j) * 1024 + n]);
  *(s16x8*)&Wt[n * 1024 + kb] = o;
}

// biasT[h*4096 + (delta+2047)] = table[bucket(delta)][h] * log2e
__global__ __launch_bounds__(256) void bias_table(const float* __restrict__ tbl,
                                                  float* __restrict__ biasT) {
  const int i = blockIdx.x * 256 + threadIdx.x;  // 65536
  const int h = i >> 12, dp = i & 4095;
  const int delta = dp - 2047;
  const int rp = delta < 0 ? -delta : delta;
  int bucket = delta > 0 ? 16 : 0;
  if (rp < 8)
    bucket += rp;
  else
    bucket += 8 + (rp >= 12) + (rp >= 16) + (rp >= 23) + (rp >= 32) +
              (rp >= 46) + (rp >= 64) + (rp >= 91);
  biasT[i] = tbl[bucket * 16 + h] * LOG2E;
}

// VT[(bh*64+d)*2048 + s] = V[(b*2048+s)*1024 + h*64 + d]
__global__ __launch_bounds__(256) void vtrans(const u16* __restrict__ V,
                                              u16* __restrict__ VT) {
  const int tid = threadIdx.x;
  const int bh = blockIdx.y;
  const int b = bh >> 4, h = bh & 15;
  const int s0 = blockIdx.x * 32;
  const int d = tid & 63;
  const int si = tid >> 6;
  s16x8 o;
#pragma unroll
  for (int j = 0; j < 8; ++j)
    o[j] = (short)V[(b * 2048 + s0 + si * 8 + j) * 1024 + h * 64 + d];
  *(s16x8*)&VT[(bh * 64 + d) * 2048 + s0 + si * 8] = o;
}

// ---------------- GEMM core: C[128x128] tile, A[M,1024] @ Bt[N,1024]^T ----------------

__device__ __forceinline__ void gemm_core(const u16* __restrict__ A,
                                          const u16* __restrict__ Bt,
                                          int m0, int n0,
                                          u16* As, u16* Bs, f32x4 acc[4][4]) {
  const int tid = threadIdx.x;
  const int w = tid >> 6, l = tid & 63, g = l >> 4, m15 = l & 15;
  const int wr = (w >> 1) * 64, wc = (w & 1) * 64;
#pragma unroll
  for (int i = 0; i < 4; ++i)
#pragma unroll
    for (int j = 0; j < 4; ++j) acc[i][j] = (f32x4){0.f, 0.f, 0.f, 0.f};

  for (int kt = 0; kt < 16; ++kt) {
    const int k0 = kt * 64;
    __syncthreads();
#pragma unroll
    for (int c = 0; c < 4; ++c) {
      const int idx = c * 256 + tid;
      const int row = idx >> 3, col16 = idx & 7;
      const int scol = col16 ^ (row & 7);
      gl_lds16(&A[(m0 + row) * 1024 + k0 + scol * 8], (char*)As + c * 4096 + w * 1024);
      gl_lds16(&Bt[(n0 + row) * 1024 + k0 + scol * 8], (char*)Bs + c * 4096 + w * 1024);
    }
    __syncthreads();
#pragma unroll
    for (int ks = 0; ks < 2; ++ks) {
      s16x8 af[4], bf[4];
#pragma unroll
      for (int mf = 0; mf < 4; ++mf) {
        const int row = wr + mf * 16 + m15;
        af[mf] = *(const s16x8*)&As[(row * 8 + ((ks * 4 + g) ^ (row & 7))) * 8];
      }
#pragma unroll
      for (int nf = 0; nf < 4; ++nf) {
        const int row = wc + nf * 16 + m15;
        bf[nf] = *(const s16x8*)&Bs[(row * 8 + ((ks * 4 + g) ^ (row & 7))) * 8];
      }
#pragma unroll
      for (int mf = 0; mf < 4; ++mf)
#pragma unroll
        for (int nf = 0; nf < 4; ++nf)
          acc[mf][nf] = MFMA16(af[mf], bf[nf], acc[mf][nf]);
    }
  }
}

// QKV: X[4096,1024] @ Wt[3072,1024]^T -> Q(scaled)/K/V bf16 [4096,1024]
__global__ __launch_bounds__(256) void gemm_qkv(const u16* __restrict__ X,
                                                const u16* __restrict__ Wt,
                                                u16* __restrict__ Q,
                                                u16* __restrict__ Kb,
                                                u16* __restrict__ Vb) {
  __shared__ u16 As[8192], Bs[8192];
  f32x4 acc[4][4];
  const int m0 = blockIdx.x * 128, n0 = blockIdx.y * 128;
  gemm_core(X, Wt, m0, n0, As, Bs, acc);

  const int tid = threadIdx.x;
  const int w = tid >> 6, l = tid & 63, g = l >> 4, m15 = l & 15;
  const int wr = (w >> 1) * 64, wc = (w & 1) * 64;
  const int nsel = n0 >> 10;
  u16* dst = nsel == 0 ? Q : (nsel == 1 ? Kb : Vb);
  const float scale = nsel == 0 ? 0.125f * LOG2E : 1.0f;
  const int ncol0 = (n0 & 1023) + wc;
#pragma unroll
  for (int mf = 0; mf < 4; ++mf) {
    const int rbase = m0 + wr + mf * 16 + g * 4;
#pragma unroll
    for (int nf = 0; nf < 4; ++nf) {
      const int col = ncol0 + nf * 16 + m15;
#pragma unroll
      for (int r = 0; r < 4; ++r)
        dst[(rbase + r) * 1024 + col] = f2bf(acc[mf][nf][r] * scale);
    }
  }
}

// out-proj: CTX[4096,1024] @ Wot[1024,1024]^T -> fp32 out
__global__ __launch_bounds__(256) void gemm_out(const u16* __restrict__ CTX,
                                                const u16* __restrict__ Wot,
                                                float* __restrict__ Out) {
  __shared__ u16 As[8192], Bs[8192];
  f32x4 acc[4][4];
  const int m0 = blockIdx.x * 128, n0 = blockIdx.y * 128;
  gemm_core(CTX, Wot, m0, n0, As, Bs, acc);

  const int tid = threadIdx.x;
  const int w = tid >> 6, l = tid & 63, g = l >> 4, m15 = l & 15;
  const int wr = (w >> 1) * 64, wc = (w & 1) * 64;
#pragma unroll
  for (int mf = 0; mf < 4; ++mf) {
    const int rbase = m0 + wr + mf * 16 + g * 4;
#pragma unroll
    for (int nf = 0; nf < 4; ++nf) {
      const int col = n0 + wc + nf * 16 + m15;
#pragma unroll
      for (int r = 0; r < 4; ++r)
        Out[(rbase + r) * 1024 + col] = acc[mf][nf][r];
    }
  }
}

// ---------------- flash attention v2 ----------------
// 1 block = (b, h, 64 q-rows); 4 waves x 16 q-rows. KV tiles of 64, double-buffered.
// No-max softmax in exp2 domain (scores bounded); bias folded into the QK
// accumulator init (constant for far tiles, per-element from L2 for <=5 near
// tiles); row-sum ls computed by a 5th PV MFMA against an all-ones B.

__global__ __launch_bounds__(256) void attn_kernel(const u16* __restrict__ Qg,
                                                   const u16* __restrict__ Kg,
                                                   const u16* __restrict__ VTg,
                                                   const float* __restrict__ biasT,
                                                   const float* __restrict__ tbl,
                                                   u16* __restrict__ CTX) {
  __shared__ u16 KT[2][4096];   // [64 kv][64 kdim] swizzled, double-buffered
  __shared__ u16 VTs[2][4096];  // [64 dv][64 kv]  swizzled, double-buffered
  __shared__ u16 P[4][1024];    // per-wave [16 q][64 kv] swizzled

  const int tid = threadIdx.x;
  const int w = tid >> 6, l = tid & 63, g = l >> 4, m15 = l & 15;
  const int bh = blockIdx.y, b = bh >> 4, h = bh & 15;
  const int q0 = blockIdx.x * 64;

  const float fpos = tbl[31 * 16 + h] * LOG2E;  // bucket for delta >= 91
  const float fneg = tbl[15 * 16 + h] * LOG2E;  // bucket for delta <= -91

  const int qrow = q0 + w * 16 + m15;
  const u16* qp = &Qg[(b * 2048 + qrow) * 1024 + h * 64 + g * 8];
  const s16x8 aq0 = *(const s16x8*)qp;
  const s16x8 aq1 = *(const s16x8*)(qp + 32);

  s16x8 vone;
#pragma unroll
  for (int j = 0; j < 8; ++j) vone[j] = (short)0x3F80;  // bf16 1.0

  f32x4 o[4];
  f32x4 ls4 = (f32x4){0.f, 0.f, 0.f, 0.f};
#pragma unroll
  for (int d = 0; d < 4; ++d) o[d] = (f32x4){0.f, 0.f, 0.f, 0.f};

  const int R0 = w * 16 + g * 4;
  u16* Pw = &P[w][0];

  const u16* Kbase = &Kg[(b * 2048) * 1024 + h * 64];
  const u16* Vbase = &VTg[bh * 64 * 2048];

#define STAGE(buf, kv0)                                                          \
  {                                                                              \
    _Pragma("unroll") for (int c = 0; c < 2; ++c) {                              \
      const int idx = c * 256 + tid;                                             \
      const int row = idx >> 3, col16 = idx & 7;                                 \
      const int scol = col16 ^ (row & 7);                                        \
      gl_lds16(&Kbase[(kv0 + row) * 1024 + scol * 8],                            \
               (char*)KT + (buf)*8192 + c * 4096 + w * 1024);                    \
      gl_lds16(&Vbase[row * 2048 + (kv0) + scol * 8],                            \
               (char*)VTs + (buf)*8192 + c * 4096 + w * 1024);                   \
    }                                                                            \
  }

  STAGE(0, 0);
  int cur = 0;
  for (int t = 0; t < 32; ++t) {
    const int kv0 = t * 64;
    __syncthreads();  // drains vmcnt -> buf[cur] ready; buf[cur^1] safe to refill
    if (t < 31) STAGE(cur ^ 1, kv0 + 64);

    const u16* KTc = &KT[cur][0];
    const u16* VTc = &VTs[cur][0];

    // S accumulator initialized with position bias
    f32x4 s[4];
    const int diff = kv0 - q0;
    if (diff >= 192 || diff <= -192) {
      const float bc = diff > 0 ? fpos : fneg;
#pragma unroll
      for (int c = 0; c < 4; ++c) s[c] = (f32x4){bc, bc, bc, bc};
    } else {
      const float* bp = &biasT[h * 4096 + kv0 + m15 - (q0 + R0) + 2047];
#pragma unroll
      for (int c = 0; c < 4; ++c)
#pragma unroll
        for (int r = 0; r < 4; ++r) s[c][r] = bp[c * 16 - r];
    }

    // S = Q K^T + bias
#pragma unroll
    for (int ks = 0; ks < 2; ++ks) {
      const s16x8 a = ks ? aq1 : aq0;
#pragma unroll
      for (int c = 0; c < 4; ++c) {
        const int row = c * 16 + m15;
        const s16x8 bk = *(const s16x8*)&KTc[(row * 8 + ((ks * 4 + g) ^ (row & 7))) * 8];
        s[c] = MFMA16(a, bk, s[c]);
      }
    }

    // p = exp2(s); store truncated bf16 to P (D-layout -> A-layout via LDS)
#pragma unroll
    for (int c = 0; c < 4; ++c) {
#pragma unroll
      for (int r = 0; r < 4; ++r) {
        const float p = __builtin_amdgcn_exp2f(s[c][r]);
        const int Rr = g * 4 + r;
        const int byt = Rr * 128 + (((c * 16 + m15) * 2) ^ ((Rr & 7) << 4));
        Pw[byt >> 1] = (u16)(__float_as_uint(p) >> 16);
      }
    }

    // O += P @ V ; ls += P @ ones
#pragma unroll
    for (int ks = 0; ks < 2; ++ks) {
      const s16x8 pa =
          *(const s16x8*)&Pw[(m15 * 128 + ((ks * 64 + g * 16) ^ ((m15 & 7) << 4))) >> 1];
#pragma unroll
      for (int d = 0; d < 4; ++d) {
        const int rowv = d * 16 + m15;
        const s16x8 bv = *(const s16x8*)&VTc[(rowv * 8 + ((ks * 4 + g) ^ (rowv & 7))) * 8];
        o[d] = MFMA16(pa, bv, o[d]);
      }
      ls4 = MFMA16(pa, vone, ls4);
    }
    cur ^= 1;
  }
#undef STAGE

  f32x4 inv;
#pragma unroll
  for (int r = 0; r < 4; ++r) inv[r] = 1.0f / ls4[r];
  const int orow = b * 2048 + q0 + w * 16 + g * 4;
  const int ocol = h * 64 + m15;
#pragma unroll
  for (int d = 0; d < 4; ++d) {
#pragma unroll
    for (int r = 0; r < 4; ++r)
      CTX[(orow + r) * 1024 + ocol + d * 16] = f2bf(o[d][r] * inv[r]);
  }
}

// ---------------- launch ----------------

extern "C" void kernel_launch(void* const* d_in, const int* in_sizes, int n_in,
                              void* d_out, int out_size, void* d_ws, size_t ws_size,
                              hipStream_t stream) {
  (void)in_sizes; (void)n_in; (void)out_size; (void)ws_size;
  const float* hs  = (const float*)d_in[0];
  const float* Wq  = (const float*)d_in[1];
  const float* Wk  = (const float*)d_in[2];
  const float* Wv  = (const float*)d_in[3];
  const float* Wo  = (const float*)d_in[4];
  const float* tbl = (const float*)d_in[5];

  char* ws = (char*)d_ws;
  u16* hsb   = (u16*)(ws);                 // 8,388,608 B  bf16 hidden
  u16* wt    = (u16*)(ws + 8388608);       // 6,291,456 B  Wq^T|Wk^T|Wv^T bf16 [3072][1024]
  u16* wot   = (u16*)(ws + 14680064);      // 2,097,152 B  Wo^T bf16
  u16* q     = (u16*)(ws + 16777216);      // 8,388,608 B  Q bf16 (scaled)
  u16* k     = (u16*)(ws + 25165824);      // 8,388,608 B  K bf16
  u16* v     = (u16*)(ws + 33554432);      // 8,388,608 B  V bf16
  u16* vt    = (u16*)(ws + 41943040);      // 8,388,608 B  V^T bf16 [32][64][2048]
  u16* ctx   = (u16*)(ws + 50331648);      // 8,388,608 B  attn output bf16
  float* biasT = (float*)(ws + 58720256);  //   262,144 B  bias table [16][4096]

  cast_hs<<<2048, 256, 0, stream>>>(hs, hsb);
  wtrans<<<dim3(16, 32), 256, 0, stream>>>(Wq, wt);
  wtrans<<<dim3(16, 32), 256, 0, stream>>>(Wk, wt + 1048576);
  wtrans<<<dim3(16, 32), 256, 0, stream>>>(Wv, wt + 2097152);
  wtrans<<<dim3(16, 32), 256, 0, stream>>>(Wo, wot);
  bias_table<<<256, 256, 0, stream>>>(tbl, biasT);
  gemm_qkv<<<dim3(32, 24), 256, 0, stream>>>(hsb, wt, q, k, v);
  vtrans<<<dim3(64, 32), 256, 0, stream>>>(v, vt);
  attn_kernel<<<dim3(32, 32), 256, 0, stream>>>(q, k, vt, biasT, tbl, ctx);
  gemm_out<<<dim3(32, 8), 256, 0, stream>>>(ctx, wot, (float*)d_out);
}

// Round 3
// 122.060 us; speedup vs baseline: 1.6727x; 1.1875x over previous
//
#include <hip/hip_runtime.h>

typedef __attribute__((ext_vector_type(8))) short s16x8;
typedef __attribute__((ext_vector_type(4))) float f32x4;
typedef __attribute__((ext_vector_type(2))) unsigned int u32x2;
typedef unsigned short u16;
typedef unsigned int u32;

#define LOG2E 1.4426950408889634f

__device__ __forceinline__ u16 f2bf(float x) {
  u32 u = __float_as_uint(x);
  u += 0x7FFFu + ((u >> 16) & 1u);
  return (u16)(u >> 16);
}

__device__ __forceinline__ u32 pack_bf_trunc(float lo, float hi) {
  return (__float_as_uint(lo) >> 16) | (__float_as_uint(hi) & 0xFFFF0000u);
}

__device__ __forceinline__ void gl_lds16(const void* g, void* l) {
  __builtin_amdgcn_global_load_lds((const __attribute__((address_space(1))) void*)g,
                                   (__attribute__((address_space(3))) void*)l, 16, 0, 0);
}

#define MFMA16(a, b, c) __builtin_amdgcn_mfma_f32_16x16x32_bf16((a), (b), (c), 0, 0, 0)

// ---------------- fused prep kernel ----------------

__global__ __launch_bounds__(256) void prep(const float* __restrict__ hs,
                                            const float* __restrict__ Wq,
                                            const float* __restrict__ Wk,
                                            const float* __restrict__ Wv,
                                            const float* __restrict__ Wo,
                                            const float* __restrict__ tbl,
                                            u16* __restrict__ hsb,
                                            u16* __restrict__ wt,
                                            u16* __restrict__ wot,
                                            float* __restrict__ biasT) {
  const int blk = blockIdx.x;
  const int tid = threadIdx.x;
  if (blk < 2048) {
    const int i = blk * 256 + tid;
    const float4* s4 = (const float4*)hs;
    float4 a = s4[i * 2];
    float4 b = s4[i * 2 + 1];
    s16x8 o;
    o[0] = (short)f2bf(a.x); o[1] = (short)f2bf(a.y);
    o[2] = (short)f2bf(a.z); o[3] = (short)f2bf(a.w);
    o[4] = (short)f2bf(b.x); o[5] = (short)f2bf(b.y);
    o[6] = (short)f2bf(b.z); o[7] = (short)f2bf(b.w);
    *(s16x8*)&hsb[i * 8] = o;
  } else if (blk < 4096) {
    int r = blk - 2048;
    const int sel = r >> 9;
    r &= 511;
    const float* W = sel == 0 ? Wq : (sel == 1 ? Wk : (sel == 2 ? Wv : Wo));
    u16* dst = sel == 3 ? wot : wt + sel * 1048576;
    const int n = (r & 15) * 64 + (tid & 63);
    const int kb = (r >> 4) * 32 + (tid >> 6) * 8;
    s16x8 o;
#pragma unroll
    for (int j = 0; j < 8; ++j) o[j] = (short)f2bf(W[(kb + j) * 1024 + n]);
    *(s16x8*)&dst[n * 1024 + kb] = o;
  } else {
    const int i = (blk - 4096) * 256 + tid;
    const int h = i >> 12, dp = i & 4095;
    const int delta = dp - 2047;
    const int rp = delta < 0 ? -delta : delta;
    int bucket = delta > 0 ? 16 : 0;
    if (rp < 8)
      bucket += rp;
    else
      bucket += 8 + (rp >= 12) + (rp >= 16) + (rp >= 23) + (rp >= 32) +
                (rp >= 46) + (rp >= 64) + (rp >= 91);
    biasT[i] = tbl[bucket * 16 + h] * LOG2E;
  }
}

// VT[(bh*64+d)*2048 + s] = V[(b*2048+s)*1024 + h*64 + d]
__global__ __launch_bounds__(256) void vtrans(const u16* __restrict__ V,
                                              u16* __restrict__ VT) {
  const int tid = threadIdx.x;
  const int bh = blockIdx.y;
  const int b = bh >> 4, h = bh & 15;
  const int s0 = blockIdx.x * 32;
  const int d = tid & 63;
  const int si = tid >> 6;
  s16x8 o;
#pragma unroll
  for (int j = 0; j < 8; ++j)
    o[j] = (short)V[(b * 2048 + s0 + si * 8 + j) * 1024 + h * 64 + d];
  *(s16x8*)&VT[(bh * 64 + d) * 2048 + s0 + si * 8] = o;
}

// ---------------- GEMM core: C[128x128] tile, A[M,1024] @ Bt[N,1024]^T ----------------

__device__ __forceinline__ void gemm_core(const u16* __restrict__ A,
                                          const u16* __restrict__ Bt,
                                          int m0, int n0,
                                          u16* As, u16* Bs, f32x4 acc[4][4]) {
  const int tid = threadIdx.x;
  const int w = tid >> 6, l = tid & 63, g = l >> 4, m15 = l & 15;
  const int wr = (w >> 1) * 64, wc = (w & 1) * 64;
#pragma unroll
  for (int i = 0; i < 4; ++i)
#pragma unroll
    for (int j = 0; j < 4; ++j) acc[i][j] = (f32x4){0.f, 0.f, 0.f, 0.f};

  for (int kt = 0; kt < 16; ++kt) {
    const int k0 = kt * 64;
    __syncthreads();
#pragma unroll
    for (int c = 0; c < 4; ++c) {
      const int idx = c * 256 + tid;
      const int row = idx >> 3, col16 = idx & 7;
      const int scol = col16 ^ (row & 7);
      gl_lds16(&A[(m0 + row) * 1024 + k0 + scol * 8], (char*)As + c * 4096 + w * 1024);
      gl_lds16(&Bt[(n0 + row) * 1024 + k0 + scol * 8], (char*)Bs + c * 4096 + w * 1024);
    }
    __syncthreads();
#pragma unroll
    for (int ks = 0; ks < 2; ++ks) {
      s16x8 af[4], bf[4];
#pragma unroll
      for (int mf = 0; mf < 4; ++mf) {
        const int row = wr + mf * 16 + m15;
        af[mf] = *(const s16x8*)&As[(row * 8 + ((ks * 4 + g) ^ (row & 7))) * 8];
      }
#pragma unroll
      for (int nf = 0; nf < 4; ++nf) {
        const int row = wc + nf * 16 + m15;
        bf[nf] = *(const s16x8*)&Bs[(row * 8 + ((ks * 4 + g) ^ (row & 7))) * 8];
      }
#pragma unroll
      for (int mf = 0; mf < 4; ++mf)
#pragma unroll
        for (int nf = 0; nf < 4; ++nf)
          acc[mf][nf] = MFMA16(af[mf], bf[nf], acc[mf][nf]);
    }
  }
}

// QKV: grid 768 blocks 1D, XCD-chunked (8m x 12n per XCD)
__global__ __launch_bounds__(256) void gemm_qkv(const u16* __restrict__ X,
                                                const u16* __restrict__ Wt,
                                                u16* __restrict__ Q,
                                                u16* __restrict__ Kb,
                                                u16* __restrict__ Vb) {
  __shared__ u16 As[8192], Bs[8192];
  f32x4 acc[4][4];
  const int flat = blockIdx.x;
  const int x = flat & 7, i = flat >> 3;  // i in [0,96)
  const int m0 = ((x & 3) * 8 + (i & 7)) * 128;
  const int n0 = ((x >> 2) * 12 + (i >> 3)) * 128;
  gemm_core(X, Wt, m0, n0, As, Bs, acc);

  const int tid = threadIdx.x;
  const int w = tid >> 6, l = tid & 63, g = l >> 4, m15 = l & 15;
  const int wr = (w >> 1) * 64, wc = (w & 1) * 64;
  const int nsel = n0 >> 10;
  u16* dst = nsel == 0 ? Q : (nsel == 1 ? Kb : Vb);
  const float scale = nsel == 0 ? 0.125f * LOG2E : 1.0f;
  const int ncol0 = (n0 & 1023) + wc;
#pragma unroll
  for (int mf = 0; mf < 4; ++mf) {
    const int rbase = m0 + wr + mf * 16 + g * 4;
#pragma unroll
    for (int nf = 0; nf < 4; ++nf) {
      const int col = ncol0 + nf * 16 + m15;
#pragma unroll
      for (int r = 0; r < 4; ++r)
        dst[(rbase + r) * 1024 + col] = f2bf(acc[mf][nf][r] * scale);
    }
  }
}

// out-proj: grid 256 blocks 1D, XCD-chunked (8m x 4n per XCD)
__global__ __launch_bounds__(256) void gemm_out(const u16* __restrict__ CTX,
                                                const u16* __restrict__ Wot,
                                                float* __restrict__ Out) {
  __shared__ u16 As[8192], Bs[8192];
  f32x4 acc[4][4];
  const int flat = blockIdx.x;
  const int x = flat & 7, i = flat >> 3;  // i in [0,32)
  const int m0 = ((x & 3) * 8 + (i & 7)) * 128;
  const int n0 = ((x >> 2) * 4 + (i >> 3)) * 128;
  gemm_core(CTX, Wot, m0, n0, As, Bs, acc);

  const int tid = threadIdx.x;
  const int w = tid >> 6, l = tid & 63, g = l >> 4, m15 = l & 15;
  const int wr = (w >> 1) * 64, wc = (w & 1) * 64;
#pragma unroll
  for (int mf = 0; mf < 4; ++mf) {
    const int rbase = m0 + wr + mf * 16 + g * 4;
#pragma unroll
    for (int nf = 0; nf < 4; ++nf) {
      const int col = n0 + wc + nf * 16 + m15;
#pragma unroll
      for (int r = 0; r < 4; ++r)
        Out[(rbase + r) * 1024 + col] = acc[mf][nf][r];
    }
  }
}

// ---------------- flash attention v3 ----------------
// 1 block = (b, h, 128 q-rows); 4 waves x 32 q-rows. KV tiles of 64, dbuf.
// Swapped QK^T: S^T = mfma(K_frag, Q_frag); lane holds q=qs*16+m15 (fixed),
// kv=c*16+g*4+r (4 adjacent per c) -> P written as 4 ds_write_b64 per 16 rows.
// No-max exp2 softmax; bias as accumulator init; ls via ones-MFMA.

__global__ __launch_bounds__(256, 2) void attn_kernel(const u16* __restrict__ Qg,
                                                      const u16* __restrict__ Kg,
                                                      const u16* __restrict__ VTg,
                                                      const float* __restrict__ biasT,
                                                      const float* __restrict__ tbl,
                                                      u16* __restrict__ CTX) {
  __shared__ u16 KT[2][4096];   // [64 kv][64 kdim] swizzled, dbuf
  __shared__ u16 VTs[2][4096];  // [64 dv][64 kv]  swizzled, dbuf
  __shared__ u16 P[4][2048];    // per-wave [32 q][64 kv] swizzled

  const int tid = threadIdx.x;
  const int w = tid >> 6, l = tid & 63, g = l >> 4, m15 = l & 15;
  // XCD-chunked remap: 512 blocks; each XCD gets 4 whole (b,h) K/V sets
  const int flat = blockIdx.x;
  const int nf_ = (flat & 7) * 64 + (flat >> 3);
  const int qblk = nf_ & 15, bh = nf_ >> 4;
  const int b = bh >> 4, h = bh & 15;
  const int qw = qblk * 128 + w * 32;  // this wave's q base (32 rows)

  const float fpos = tbl[31 * 16 + h] * LOG2E;  // delta >= 91 bucket
  const float fneg = tbl[15 * 16 + h] * LOG2E;  // delta <= -91 bucket

  // Q fragments, B-operand layout (col=q=m15, k=ks*32+g*8+j), 2 q-subfrags
  s16x8 aq[2][2];
#pragma unroll
  for (int qs = 0; qs < 2; ++qs) {
    const u16* qp = &Qg[(b * 2048 + qw + qs * 16 + m15) * 1024 + h * 64 + g * 8];
    aq[qs][0] = *(const s16x8*)qp;
    aq[qs][1] = *(const s16x8*)(qp + 32);
  }

  s16x8 vone;
#pragma unroll
  for (int j = 0; j < 8; ++j) vone[j] = (short)0x3F80;  // bf16 1.0

  f32x4 o[2][4];
  f32x4 ls4[2];
#pragma unroll
  for (int qs = 0; qs < 2; ++qs) {
    ls4[qs] = (f32x4){0.f, 0.f, 0.f, 0.f};
#pragma unroll
    for (int d = 0; d < 4; ++d) o[qs][d] = (f32x4){0.f, 0.f, 0.f, 0.f};
  }

  u16* Pw = &P[w][0];
  const int pswz = (m15 & 7) << 4;

  const u16* Kbase = &Kg[(b * 2048) * 1024 + h * 64];
  const u16* Vbase = &VTg[bh * 64 * 2048];

#define STAGE(buf, kv0)                                                          \
  {                                                                              \
    _Pragma("unroll") for (int c = 0; c < 2; ++c) {                              \
      const int idx = c * 256 + tid;                                             \
      const int row = idx >> 3, col16 = idx & 7;                                 \
      const int scol = col16 ^ (row & 7);                                        \
      gl_lds16(&Kbase[(kv0 + row) * 1024 + scol * 8],                            \
               (char*)KT + (buf)*8192 + c * 4096 + w * 1024);                    \
      gl_lds16(&Vbase[row * 2048 + (kv0) + scol * 8],                            \
               (char*)VTs + (buf)*8192 + c * 4096 + w * 1024);                   \
    }                                                                            \
  }

  STAGE(0, 0);
  int cur = 0;
  for (int t = 0; t < 32; ++t) {
    const int kv0 = t * 64;
    __syncthreads();  // drains vmcnt: buf[cur] ready; buf[cur^1] free
    if (t < 31) STAGE(cur ^ 1, kv0 + 64);

    const u16* KTc = &KT[cur][0];
    const u16* VTc = &VTs[cur][0];

    // S^T accumulators init with bias; lane: q=qs*16+m15, kv=c*16+g*4+r
    f32x4 s[2][4];
    const int diff = kv0 - qw;
    if (diff <= -160 || diff >= 128) {
      const float bc = diff > 0 ? fpos : fneg;
#pragma unroll
      for (int qs = 0; qs < 2; ++qs)
#pragma unroll
        for (int c = 0; c < 4; ++c) s[qs][c] = (f32x4){bc, bc, bc, bc};
    } else {
#pragma unroll
      for (int qs = 0; qs < 2; ++qs) {
        const float* bp = &biasT[h * 4096 + kv0 + g * 4 - qw - qs * 16 - m15 + 2047];
#pragma unroll
        for (int c = 0; c < 4; ++c)
#pragma unroll
          for (int r = 0; r < 4; ++r) s[qs][c][r] = bp[c * 16 + r];
      }
    }

    // S^T += K Q^T  (A = K-frag, B = Q-frag; 8 LDS reads feed 16 MFMAs)
#pragma unroll
    for (int ks = 0; ks < 2; ++ks) {
#pragma unroll
      for (int c = 0; c < 4; ++c) {
        const int row = c * 16 + m15;
        const s16x8 bk = *(const s16x8*)&KTc[(row * 8 + ((ks * 4 + g) ^ (row & 7))) * 8];
        s[0][c] = MFMA16(bk, aq[0][ks], s[0][c]);
        s[1][c] = MFMA16(bk, aq[1][ks], s[1][c]);
      }
    }

    // p = exp2(s); pack adjacent-kv pairs; b64 writes to P [32 q][64 kv]
#pragma unroll
    for (int qs = 0; qs < 2; ++qs) {
      const int q32 = qs * 16 + m15;
#pragma unroll
      for (int c = 0; c < 4; ++c) {
        const u32 w0 = pack_bf_trunc(__builtin_amdgcn_exp2f(s[qs][c][0]),
                                     __builtin_amdgcn_exp2f(s[qs][c][1]));
        const u32 w1 = pack_bf_trunc(__builtin_amdgcn_exp2f(s[qs][c][2]),
                                     __builtin_amdgcn_exp2f(s[qs][c][3]));
        const int byt = q32 * 128 + c * 32 + g * 8;
        *(u32x2*)((char*)Pw + (byt ^ pswz)) = (u32x2){w0, w1};
      }
    }

    // O += P @ V ; ls += P @ ones  (12 LDS reads feed 20 MFMAs)
#pragma unroll
    for (int ks = 0; ks < 2; ++ks) {
      s16x8 pa[2];
#pragma unroll
      for (int qs = 0; qs < 2; ++qs) {
        const int byt = (qs * 16 + m15) * 128 + ks * 64 + g * 16;
        pa[qs] = *(const s16x8*)((const char*)Pw + (byt ^ pswz));
      }
#pragma unroll
      for (int d = 0; d < 4; ++d) {
        const int rowv = d * 16 + m15;
        const s16x8 bv = *(const s16x8*)&VTc[(rowv * 8 + ((ks * 4 + g) ^ (rowv & 7))) * 8];
        o[0][d] = MFMA16(pa[0], bv, o[0][d]);
        o[1][d] = MFMA16(pa[1], bv, o[1][d]);
      }
      ls4[0] = MFMA16(pa[0], vone, ls4[0]);
      ls4[1] = MFMA16(pa[1], vone, ls4[1]);
    }
    cur ^= 1;
  }
#undef STAGE

#pragma unroll
  for (int qs = 0; qs < 2; ++qs) {
    f32x4 inv;
#pragma unroll
    for (int r = 0; r < 4; ++r) inv[r] = 1.0f / ls4[qs][r];
    const int orow = b * 2048 + qw + qs * 16 + g * 4;
    const int ocol = h * 64 + m15;
#pragma unroll
    for (int d = 0; d < 4; ++d) {
#pragma unroll
      for (int r = 0; r < 4; ++r)
        CTX[(orow + r) * 1024 + ocol + d * 16] = f2bf(o[qs][d][r] * inv[r]);
    }
  }
}

// ---------------- launch ----------------

extern "C" void kernel_launch(void* const* d_in, const int* in_sizes, int n_in,
                              void* d_out, int out_size, void* d_ws, size_t ws_size,
                              hipStream_t stream) {
  (void)in_sizes; (void)n_in; (void)out_size; (void)ws_size;
  const float* hs  = (const float*)d_in[0];
  const float* Wq  = (const float*)d_in[1];
  const float* Wk  = (const float*)d_in[2];
  const float* Wv  = (const float*)d_in[3];
  const float* Wo  = (const float*)d_in[4];
  const float* tbl = (const float*)d_in[5];

  char* ws = (char*)d_ws;
  u16* hsb   = (u16*)(ws);                 // 8 MB  bf16 hidden
  u16* wt    = (u16*)(ws + 8388608);       // 6 MB  Wq^T|Wk^T|Wv^T bf16
  u16* wot   = (u16*)(ws + 14680064);      // 2 MB  Wo^T bf16
  u16* q     = (u16*)(ws + 16777216);      // 8 MB  Q bf16 (scaled)
  u16* k     = (u16*)(ws + 25165824);      // 8 MB  K bf16
  u16* v     = (u16*)(ws + 33554432);      // 8 MB  V bf16
  u16* vt    = (u16*)(ws + 41943040);      // 8 MB  V^T bf16 [32][64][2048]
  u16* ctx   = (u16*)(ws + 50331648);      // 8 MB  attn output bf16
  float* biasT = (float*)(ws + 58720256);  // 256 KB bias table [16][4096]

  prep<<<4352, 256, 0, stream>>>(hs, Wq, Wk, Wv, Wo, tbl, hsb, wt, wot, biasT);
  gemm_qkv<<<768, 256, 0, stream>>>(hsb, wt, q, k, v);
  vtrans<<<dim3(64, 32), 256, 0, stream>>>(v, vt);
  attn_kernel<<<512, 256, 0, stream>>>(q, k, vt, biasT, tbl, ctx);
  gemm_out<<<256, 256, 0, stream>>>(ctx, wot, (float*)d_out);
}